// Round 1
// 445.447 us; speedup vs baseline: 1.1954x; 1.1954x over previous
//
#include <hip/hip_runtime.h>

// Spatial correlation (cost volume), B=8 C=128 H=W=96, patch 9x9, 3x3 box, pad 1.
// out[b,di,dj,y,x] = sum_{i,j in 0..2} P[b,di,dj,y+i,x+j]
// P[b,di,dj,y',x'] = sum_c q_pad[y',x'] * k_pad[y'+di, x'+dj]   (padded 98x98 grid)
//
// R3: the R2 kernel was latency-bound (VALUBusy 11.6%, HBM 11%, LDS ~30%,
// nothing saturated): per pass it ran barrier -> stage (vmcnt(0)-drained
// global loads) -> barrier -> short compute, 8 passes in lockstep.
// This version software-pipelines (T14 async-STAGE split + LDS double
// buffer): issue pass n+1's global loads into registers BEFORE computing
// pass n, ds_write them after, ONE barrier per pass. ks stride 48 -> 24
// (the 48-stride wasted half the array; packed 24-stride is still exactly
// 2 words/bank for the wave64 b128 reads) so both buffers fit in 53 KiB.

#define BATCH 8
#define CHN   128
#define IMG   96
#define TILE  16    // P-tile edge (padded-grid points) per block
#define OTILE 14    // output-tile edge per block (TILE - 2)
#define NC    8     // channels staged per pass
#define CHALF 64    // channels per block (2-way split)
#define NCB   (CHALF / NC)
#define KT    24    // k-tile edge (TILE + 8)
#define QTP   16    // q-tile col stride
#define NTHR  512

struct Tiles {
  float qs[NC][TILE][QTP];   //  8192 B
  float ks[NC][KT][KT];      // 18432 B (packed; 24-word row stride)
};                           // 26624 B; two buffers = 53248 B

struct StageRegs {
  float q[4];   // NC*TILE*TILE / NTHR = 4
  float k[9];   // NC*KT*KT   / NTHR = 9
};

__device__ inline void stage_load(const float* __restrict__ qg, const float* __restrict__ kg,
                                  StageRegs& r, int cbase, int b, int X0, int Y0, int tid) {
#pragma unroll
  for (int i = 0; i < 4; ++i) {
    const int idx = tid + i * NTHR;
    const int c = idx >> 8;
    const int rem = idx & 255;
    const int rr = rem >> 4, col = rem & 15;
    const int gy = Y0 + rr - 1, gx = X0 + col - 1;
    float v = 0.f;
    if ((unsigned)gy < IMG && (unsigned)gx < IMG)
      v = qg[((size_t)(b * CHN + cbase + c) * IMG + gy) * IMG + gx];
    r.q[i] = v;
  }
#pragma unroll
  for (int i = 0; i < 9; ++i) {
    const int idx = tid + i * NTHR;
    const int c = idx / (KT * KT);
    const int rem = idx - c * (KT * KT);
    const int rr = rem / KT, col = rem - rr * KT;
    const int gy = Y0 + rr - 5, gx = X0 + col - 5;
    float v = 0.f;
    if ((unsigned)gy < IMG && (unsigned)gx < IMG)
      v = kg[((size_t)(b * CHN + cbase + c) * IMG + gy) * IMG + gx];
    r.k[i] = v;
  }
}

__device__ inline void stage_write(Tiles& t, const StageRegs& r, int tid) {
  float* qflat = &t.qs[0][0][0];
#pragma unroll
  for (int i = 0; i < 4; ++i) qflat[tid + i * NTHR] = r.q[i];
  float* kflat = &t.ks[0][0][0];
#pragma unroll
  for (int i = 0; i < 9; ++i) kflat[tid + i * NTHR] = r.k[i];
}

__device__ constexpr int di_lo_o(int OB, int d) {
  const int di = OB / 9 + d;
  return OB > di * 9 ? OB : di * 9;
}
__device__ constexpr int di_hi_o(int OB, int ON, int d) {
  const int di = OB / 9 + d;
  return (OB + ON) < (di * 9 + 9) ? (OB + ON) : (di * 9 + 9);
}
__device__ constexpr bool h_needed(int OB, int ON, int d, int h) {
  const int lo = di_lo_o(OB, d), hi = di_hi_o(OB, ON, d);
  if (lo >= hi) return false;
  const int di = OB / 9 + d;
  const int clo = lo - di * 9, chi = (hi - 1 - di * 9) + 3;
  return (4 * h <= chi) && (4 * h + 3 >= clo);
}

template <int OB, int ON, int d>
__device__ inline void do_row(const Tiles& t, int c, int py, int xg4,
                              const float (&qa)[4], float (&acc)[ON * 4]) {
  if constexpr (di_lo_o(OB, d) < di_hi_o(OB, ON, d)) {
    constexpr int DI0 = OB / 9;
    float kd[12];
    if constexpr (h_needed(OB, ON, d, 0)) *(float4*)&kd[0] = *(const float4*)&t.ks[c][py + DI0 + d][xg4 + 0];
    if constexpr (h_needed(OB, ON, d, 1)) *(float4*)&kd[4] = *(const float4*)&t.ks[c][py + DI0 + d][xg4 + 4];
    if constexpr (h_needed(OB, ON, d, 2)) *(float4*)&kd[8] = *(const float4*)&t.ks[c][py + DI0 + d][xg4 + 8];
#pragma unroll
    for (int oi = 0; oi < ON; ++oi) {
      if ((OB + oi) / 9 == DI0 + d) {            // constant-folded after unroll
        const int dj = (OB + oi) - ((OB + oi) / 9) * 9;
#pragma unroll
        for (int p = 0; p < 4; ++p)
          acc[oi * 4 + p] = __builtin_fmaf(qa[p], kd[dj + p], acc[oi * 4 + p]);
      }
    }
  }
}

template <int OB, int ON>
__device__ void run(const float* __restrict__ qg, const float* __restrict__ kg,
                    float* __restrict__ out, Tiles* __restrict__ t,
                    int b, int cbase0, int X0, int Y0, int tid, int lane) {
  const int xg  = lane & 3;    // 4 x-groups of 4 points = 16 cols
  const int py  = lane >> 2;   // 16 rows
  const int xg4 = xg * 4;

  float acc[ON * 4];
#pragma unroll
  for (int i = 0; i < ON * 4; ++i) acc[i] = 0.f;

  // Prologue: fill buffer 0.
  StageRegs r;
  stage_load(qg, kg, r, cbase0, b, X0, Y0, tid);
  stage_write(t[0], r, tid);
  __syncthreads();

  for (int cb = 0; cb < NCB; ++cb) {
    const Tiles& tc = t[cb & 1];
    // Issue next pass's global loads NOW; their latency hides under compute.
    if (cb + 1 < NCB)
      stage_load(qg, kg, r, cbase0 + (cb + 1) * NC, b, X0, Y0, tid);
#pragma unroll 2
    for (int c = 0; c < NC; ++c) {
      float qa[4];
      *(float4*)qa = *(const float4*)&tc.qs[c][py][xg4];
      do_row<OB, ON, 0>(tc, c, py, xg4, qa, acc);
      do_row<OB, ON, 1>(tc, c, py, xg4, qa, acc);
      do_row<OB, ON, 2>(tc, c, py, xg4, qa, acc);
    }
    // Write-late: by now the loads have (mostly) landed; vmcnt wait is short.
    if (cb + 1 < NCB)
      stage_write(t[(cb + 1) & 1], r, tid);
    __syncthreads();                     // single barrier per pass
  }

  // Epilogue: 3x3 box sum entirely with shuffles (no LDS, no barriers).
  const int srcx = (xg < 3) ? (lane + 1) : lane;   // xg==3 values unused
  const int gy   = Y0 + py;
  const bool rowok = (py < OTILE) && (gy < IMG);
  float* obase = out + ((size_t)b * 81 * IMG + gy) * IMG + X0;
#pragma unroll
  for (int oi = 0; oi < ON; ++oi) {
    const float a0 = acc[oi * 4 + 0], a1 = acc[oi * 4 + 1];
    const float a2 = acc[oi * 4 + 2], a3 = acc[oi * 4 + 3];
    const float a0n = __shfl(a0, srcx);
    const float a1n = __shfl(a1, srcx);
    float s0 = a0 + a1 + a2;
    float s1 = a1 + a2 + a3;
    float s2 = a2 + a3 + a0n;
    float s3 = a3 + a0n + a1n;
    s0 += __shfl_down(s0, 4) + __shfl_down(s0, 8);
    s1 += __shfl_down(s1, 4) + __shfl_down(s1, 8);
    s2 += __shfl_down(s2, 4) + __shfl_down(s2, 8);
    s3 += __shfl_down(s3, 4) + __shfl_down(s3, 8);
    if (rowok) {
      const int o = OB + oi;
      float* orow = obase + (size_t)o * IMG * IMG;
      if (xg4 + 0 < OTILE && X0 + xg4 + 0 < IMG) atomicAdd(&orow[xg4 + 0], s0);
      if (xg4 + 1 < OTILE && X0 + xg4 + 1 < IMG) atomicAdd(&orow[xg4 + 1], s1);
      if (xg4 + 2 < OTILE && X0 + xg4 + 2 < IMG) atomicAdd(&orow[xg4 + 2], s2);
      if (xg4 + 3 < OTILE && X0 + xg4 + 3 < IMG) atomicAdd(&orow[xg4 + 3], s3);
    }
  }
}

__global__ __launch_bounds__(NTHR, 4) void spatial_corr_kernel(const float* __restrict__ q,
                                                               const float* __restrict__ k,
                                                               float* __restrict__ out) {
  __shared__ Tiles t[2];
  const int tid  = threadIdx.x;
  const int w    = tid >> 6;
  const int lane = tid & 63;
  const int b      = blockIdx.z >> 1;
  const int cbase0 = (blockIdx.z & 1) * CHALF;
  const int X0 = blockIdx.x * OTILE;
  const int Y0 = blockIdx.y * OTILE;
  // 8 waves x (11,10,...,10) offsets; every window spans exactly 2 di rows.
  if (w == 0)      run<0,  11>(q, k, out, t, b, cbase0, X0, Y0, tid, lane);
  else if (w == 1) run<11, 10>(q, k, out, t, b, cbase0, X0, Y0, tid, lane);
  else if (w == 2) run<21, 10>(q, k, out, t, b, cbase0, X0, Y0, tid, lane);
  else if (w == 3) run<31, 10>(q, k, out, t, b, cbase0, X0, Y0, tid, lane);
  else if (w == 4) run<41, 10>(q, k, out, t, b, cbase0, X0, Y0, tid, lane);
  else if (w == 5) run<51, 10>(q, k, out, t, b, cbase0, X0, Y0, tid, lane);
  else if (w == 6) run<61, 10>(q, k, out, t, b, cbase0, X0, Y0, tid, lane);
  else             run<71, 10>(q, k, out, t, b, cbase0, X0, Y0, tid, lane);
}

extern "C" void kernel_launch(void* const* d_in, const int* in_sizes, int n_in,
                              void* d_out, int out_size, void* d_ws, size_t ws_size,
                              hipStream_t stream) {
  const float* q = (const float*)d_in[0];
  const float* k = (const float*)d_in[1];
  // d_in[2] (value) is unused by the reference output.
  float* out = (float*)d_out;
  hipMemsetAsync(out, 0, (size_t)out_size * sizeof(float), stream);
  dim3 grid(7, 7, BATCH * 2);   // x-tiles, y-tiles, batch x channel-half
  dim3 block(NTHR);
  hipLaunchKernelGGL(spatial_corr_kernel, grid, block, 0, stream, q, k, out);
}